// Round 18
// baseline (26.145 us; speedup 1.0000x reference)
//
#include <hip/hip_runtime.h>
#include <hip/hip_fp16.h>

// Joint bilateral filter, K=5, zero padding. R17 fp16-packed body, TALLER TILE:
// 512-thread blocks, 128x16 output tile, TR=20 staged rows -> y-halo refetch
// 1.50x -> 1.25x (-17% L2-fill traffic, the last standing limiter hypothesis).
// 26.6KB LDS, 4 blocks/CU (thread cap) = 32 waves/CU; grid 900 <= 1024 slots.
// t: (2,3,720,1280) f32; v: (2,2,720,1280) f32; out: (2,2,720,1280) f32
// coeff = max(0.875 - 50*sum_c (t_c-ts_c)^2, 0); out = sum(vs*coeff)/sum(coeff)
// Lessons kept: no launch_bounds min-waves (R6/R9), reg-staged MLP loads (R13),
// bijective XCD swizzle for 900%8!=0 (ERRATA #11), fresh-scope arrays (R7).

typedef _Float16 f16x2 __attribute__((ext_vector_type(2)));
typedef _Float16 f16x4 __attribute__((ext_vector_type(4)));
typedef _Float16 f16x8 __attribute__((ext_vector_type(8)));

static __device__ __forceinline__ f16x2 pkrtz(float a, float b) {
    return __builtin_bit_cast(f16x2, __builtin_amdgcn_cvt_pkrtz(a, b));
}

constexpr int H_ = 720;
constexpr int W_ = 1280;
constexpr int HW = H_ * W_;
constexpr float COEF0 = 0.875f;
constexpr float SIDIV = 50.0f;

constexpr int TC  = 132;            // staged cols: global gx0-2 .. gx0+129
constexpr int TCB = 136;            // ldsB padded stride (16B-aligned rows)
constexpr int TR  = 20;             // staged rows: gy0-2 .. gy0+17
constexpr int NK  = 34;             // aligned global chunks per row (gx0-4+4k)
constexpr int NITEM = 3 * TR * NK;  // 2040 staging items (t01 / t2 / v01)
constexpr int NWG = 900;            // 10 x-tiles * 45 y-tiles * 2 images
constexpr int QX = NWG / 8;         // 112
constexpr int RX = NWG % 8;         // 4

__global__ __launch_bounds__(512)
void jbf_h16(const float* __restrict__ t, const float* __restrict__ v,
             float* __restrict__ out) {
    __shared__ alignas(16) f16x2    ldsA[TR][TC];   // (t0,t1)  10560 B
    __shared__ alignas(16) _Float16 ldsB[TR][TCB];  // t2        5440 B
    __shared__ alignas(16) f16x2    ldsC[TR][TC];   // (v0,v1)  10560 B

    // bijective XCD swizzle for NWG=900 (900%8!=0): XCD i owns a contiguous band
    const int xcd = (int)blockIdx.x & 7;
    const int lid = (int)blockIdx.x >> 3;
    const int wgid = (xcd < RX ? xcd * (QX + 1) : RX * (QX + 1) + (xcd - RX) * QX) + lid;
    const int n   = wgid / 450;
    const int rem = wgid % 450;
    const int gy0 = (rem / 10) * 16;
    const int gx0 = (rem % 10) * 128;

    const float* tn = t + (size_t)n * 3 * HW;
    const float* vn = v + (size_t)n * 2 * HW;
    float*       on = out + (size_t)n * 2 * HW;

    const int tid = threadIdx.x;

    // ---- stage phase 1: issue all global loads (sets: 0=t01, 1=t2, 2=v01) ----
    float4 pA[4], pB[4];
#pragma unroll
    for (int it = 0; it < 4; ++it) {
        const int i  = tid + it * 512;       // it<3 always < NITEM; it==3 guarded
        const int st = i / 680;              // 680 = TR*NK
        const int idx = i % 680;
        const int rr = idx / 34, k = idx % 34;
        const int gy = gy0 - 2 + rr;
        const int gx = gx0 - 4 + 4 * k;
        pA[it] = make_float4(0.f, 0.f, 0.f, 0.f);
        pB[it] = make_float4(0.f, 0.f, 0.f, 0.f);
        const bool live = (it < 3 || i < NITEM) &&
                          ((unsigned)gy < (unsigned)H_) &&
                          ((unsigned)gx < (unsigned)(W_ - 3));
        if (live) {
            const float* base = tn + gy * W_ + gx;
            if (st == 0) {
                pA[it] = *(const float4*)(base);
                pB[it] = *(const float4*)(base + HW);
            } else if (st == 1) {
                pA[it] = *(const float4*)(base + 2 * HW);
            } else {
                const float* vb = vn + gy * W_ + gx;
                pA[it] = *(const float4*)(vb);
                pB[it] = *(const float4*)(vb + HW);
            }
        }
    }

    // ---- stage phase 2: convert to fp16 and write LDS (shifted layout) ----
#pragma unroll
    for (int it = 0; it < 4; ++it) {
        const int i = tid + it * 512;
        if (it < 3 || i < NITEM) {
            const int st = i / 680;
            const int idx = i % 680;
            const int rr = idx / 34, k = idx % 34;
            const float4 a = pA[it], b = pB[it];
            if (st == 1) {
                const f16x2 q0 = pkrtz(a.x, a.y);
                const f16x2 q1 = pkrtz(a.z, a.w);
                if (k > 0)      *(f16x2*)&ldsB[rr][4 * k - 2] = q0;
                if (k < NK - 1) *(f16x2*)&ldsB[rr][4 * k]     = q1;
            } else {
                const f16x2 p0 = pkrtz(a.x, b.x);
                const f16x2 p1 = pkrtz(a.y, b.y);
                const f16x2 p2 = pkrtz(a.z, b.z);
                const f16x2 p3 = pkrtz(a.w, b.w);
                f16x2 (*dst)[TC] = (st == 0) ? ldsA : ldsC;
                if (k > 0) {
                    f16x4 lo = {p0.x, p0.y, p1.x, p1.y};
                    *(f16x4*)&dst[rr][4 * k - 2] = lo;
                }
                if (k < NK - 1) {
                    f16x4 hi = {p2.x, p2.y, p3.x, p3.y};
                    *(f16x4*)&dst[rr][4 * k] = hi;
                }
            }
        }
    }
    __syncthreads();

    // ---------------- compute 4 px ----------------
    const int tx = tid & 31;                 // x-group
    const int ty = tid >> 5;                 // output row 0..15
    const int lc = 4 * tx;                   // window base staged col

    float num0[4] = {0.f, 0.f, 0.f, 0.f};
    float num1[4] = {0.f, 0.f, 0.f, 0.f};
    float den[4]  = {0.f, 0.f, 0.f, 0.f};
    f16x2 c01[4];
    float c2f[4];

#define LOADW(LR)                                                              \
    f16x2 a01[8]; f16x2 uv[8]; float w2f[8];                                   \
    {                                                                          \
        *(f16x8*)&a01[0] = *(const f16x8*)&ldsA[LR][lc];                       \
        *(f16x8*)&a01[4] = *(const f16x8*)&ldsA[LR][lc + 4];                   \
        f16x4 b0 = *(const f16x4*)&ldsB[LR][lc];                               \
        f16x4 b1 = *(const f16x4*)&ldsB[LR][lc + 4];                           \
        *(f16x8*)&uv[0] = *(const f16x8*)&ldsC[LR][lc];                        \
        *(f16x8*)&uv[4] = *(const f16x8*)&ldsC[LR][lc + 4];                    \
        _Pragma("unroll") for (int m_ = 0; m_ < 4; ++m_) {                     \
            w2f[m_]     = (float)b0[m_];                                       \
            w2f[m_ + 4] = (float)b1[m_];                                       \
        }                                                                      \
    }

#define COMPW()                                                                \
    _Pragma("unroll") for (int dx_ = 0; dx_ < 5; ++dx_)                        \
        _Pragma("unroll") for (int j_ = 0; j_ < 4; ++j_) {                     \
            const int k_ = dx_ + j_;                                           \
            const f16x2 d01 = a01[k_] - c01[j_];                               \
            const float d2  = w2f[k_] - c2f[j_];                               \
            const float diff = __builtin_amdgcn_fdot2(d01, d01, d2 * d2, false);\
            const float c_ = fmaxf(fmaf(diff, -SIDIV, COEF0), 0.f);            \
            num0[j_] = fmaf((float)uv[k_].x, c_, num0[j_]);                    \
            num1[j_] = fmaf((float)uv[k_].y, c_, num1[j_]);                    \
            den[j_] += c_;                                                     \
        }

    {   // r = 2 first: its window contains the centers (elem j+2 = pixel j)
        const int lr = ty + 2;
        LOADW(lr)
#pragma unroll
        for (int j = 0; j < 4; ++j) {
            c01[j] = a01[j + 2];
            c2f[j] = w2f[j + 2];
        }
        COMPW()
    }
#pragma unroll 1
    for (int i2 = 0; i2 < 4; ++i2) {
        const int r = i2 + (i2 >> 1);        // {0,1,3,4}
        const int lr = ty + r;
        LOADW(lr)
        COMPW()
    }

    float4 o0, o1;
    float* o0a = (float*)&o0;
    float* o1a = (float*)&o1;
#pragma unroll
    for (int j = 0; j < 4; ++j) {
        const float rcp = 1.f / den[j];
        // mimic the reference's fp16 round-trip
        o0a[j] = __half2float(__float2half(num0[j] * rcp));
        o1a[j] = __half2float(__float2half(num1[j] * rcp));
    }
    const int ctr = (gy0 + ty) * W_ + gx0 + 4 * tx;
    *(float4*)(on + ctr) = o0;
    *(float4*)(on + HW + ctr) = o1;
}

extern "C" void kernel_launch(void* const* d_in, const int* in_sizes, int n_in,
                              void* d_out, int out_size, void* d_ws, size_t ws_size,
                              hipStream_t stream) {
    const float* t = (const float*)d_in[0];
    const float* v = (const float*)d_in[1];
    float* out = (float*)d_out;

    // 10 x-tiles * 45 y-tiles * 2 images = 900 blocks of 512 (XCD-swizzled)
    jbf_h16<<<NWG, 512, 0, stream>>>(t, v, out);
}